// Round 2
// baseline (306.250 us; speedup 1.0000x reference)
//
#include <hip/hip_runtime.h>

static constexpr int Tn = 2000;
static constexpr int Bn = 512;
static constexpr int Cn = 29;
static constexpr int Ln = 150;
static constexpr float LOG2E_F = 1.4426950408889634f;
static constexpr float LN2_F   = 0.6931471805599453f;
static constexpr float NEGV    = -1e30f;

// workspace layout (floats)
static constexpr int WS_DEN_F = 0;                      // 512*32
static constexpr int WS_DEN_B = 512 * 32;               // 512*32
static constexpr int WS_NUM_F = 2 * 512 * 32;           // 512*160
static constexpr int WS_NUM_B = 2 * 512 * 32 + 512 * 160;
// total = 196608 floats = 768 KiB

#if __has_builtin(__builtin_amdgcn_exp2f)
#define FEXP2(x) __builtin_amdgcn_exp2f(x)
#else
#define FEXP2(x) exp2f(x)
#endif
#if __has_builtin(__builtin_amdgcn_logf)
#define FLOG2(x) __builtin_amdgcn_logf(x)
#else
#define FLOG2(x) log2f(x)
#endif

// log2(2^x + 2^y), safe for finite "NEG" sentinels (-1e30)
__device__ __forceinline__ float ladd2(float x, float y) {
    float m = fmaxf(x, y);
    float d = fminf(x, y) - m;   // <= 0, finite
    return m + FLOG2(1.0f + FEXP2(d));
}

__global__ __launch_bounds__(64)
void asg_scan(const float* __restrict__ inp, const float* __restrict__ tr,
              const int* __restrict__ tg, float* __restrict__ ws)
{
    const int tid = threadIdx.x;
    const int bid = blockIdx.x;
    __shared__ float wbuf[64];

    if (bid < 512) {
        // ================= DENOMINATOR =================
        // 2 groups of 32 lanes per wave; group = (dir, b); lane i = state.
        const int g   = tid >> 5;
        const int i   = tid & 31;
        const int gid = (bid << 1) | g;     // 0..1023
        const int dir = gid >> 9;           // 0 = fwd, 1 = bwd
        const int b   = gid & 511;
        const int ii  = (i < Cn) ? i : (Cn - 1);

        // E[j] = exp(trans[row][col]): fwd lane i holds row i (sum over j),
        // bwd lane j holds column j (sum over i).
        float E[Cn];
#pragma unroll
        for (int j = 0; j < Cn; ++j) {
            float tv = dir ? tr[(1 + j) * Cn + ii] : tr[(1 + ii) * Cn + j];
            E[j] = FEXP2(LOG2E_F * tv);
        }

        float cur;
        if (dir == 0)
            cur = (i < Cn) ? LOG2E_F * (inp[(size_t)b * Cn + i] + tr[i]) : NEGV;
        else
            cur = (i < Cn) ? 0.0f : NEGV;

        const float* eb = inp + (size_t)b * Cn + ii;
        const int t0    = dir ? (Tn - 1) : 1;
        const int dt    = dir ? -1 : 1;
        const int steps = dir ? 1000 : 999;   // fwd -> alpha_999, bwd -> beta_999

        float ce[8], ne[8];
#pragma unroll
        for (int u = 0; u < 8; ++u) {
            int tt = t0 + u * dt; tt = max(0, min(Tn - 1, tt));
            ce[u] = LOG2E_F * eb[(size_t)tt * (Bn * Cn)];
        }
        const float* wb = &wbuf[g << 5];

        for (int s = 0; s < steps; s += 8) {
#pragma unroll
            for (int u = 0; u < 8; ++u) {       // prefetch 8 steps ahead
                int tt = t0 + (s + 8 + u) * dt; tt = max(0, min(Tn - 1, tt));
                ne[u] = LOG2E_F * eb[(size_t)tt * (Bn * Cn)];
            }
#pragma unroll
            for (int u = 0; u < 8; ++u) {
                if (s + u < steps) {            // uniform branch
                    const float e2 = ce[u];
                    float v = dir ? (cur + e2) : cur;
                    float M = __shfl(v, tid & 32);          // lane-0 shift (spread bounded)
                    float w = FEXP2(v - M);                 // pad lanes: exp2(-1e30)=0
                    wbuf[tid] = w;
                    __asm__ volatile("s_waitcnt lgkmcnt(0)" ::: "memory");
                    __builtin_amdgcn_sched_barrier(0);
                    float a0 = 0.f, a1 = 0.f, a2 = 0.f, a3 = 0.f;
                    const float4* wb4 = reinterpret_cast<const float4*>(wb);
#pragma unroll
                    for (int q = 0; q < 8; ++q) {
                        float4 wq = wb4[q];
                        a0 = fmaf(wq.x, E[4 * q + 0], a0);
                        if (q < 7) {
                            a1 = fmaf(wq.y, E[4 * q + 1], a1);
                            a2 = fmaf(wq.z, E[4 * q + 2], a2);
                            a3 = fmaf(wq.w, E[4 * q + 3], a3);
                        }
                    }
                    float y = M + FLOG2((a0 + a1) + (a2 + a3));
                    cur = dir ? y : (y + e2);
                }
            }
#pragma unroll
            for (int u = 0; u < 8; ++u) ce[u] = ne[u];
        }
        if (i < Cn)
            ws[(dir ? WS_DEN_B : WS_DEN_F) + b * 32 + i] = cur;
    } else {
        // ================= NUMERATOR =================
        // 1 wave = one (dir, b); lane k owns labels l = 3k..3k+2 (k < 50 active).
        const int nid = bid - 512;
        const int dir = nid >> 9;
        const int b   = nid & 511;
        const int k   = tid;
        const int* tb = tg + b * Ln;

        const int l0 = 3 * k, l1 = 3 * k + 1, l2 = 3 * k + 2;
        const int t0i = (l0 < Ln) ? tb[l0] : 0;
        const int t1i = (l1 < Ln) ? tb[l1] : 0;
        const int t2i = (l2 < Ln) ? tb[l2] : 0;
        const float s0c = LOG2E_F * tr[(1 + t0i) * Cn + t0i];
        const float s1c = LOG2E_F * tr[(1 + t1i) * Cn + t1i];
        const float s2c = LOG2E_F * tr[(1 + t2i) * Cn + t2i];
        const int   p0  = (l0 >= 1 && l0 < Ln) ? tb[l0 - 1] : 0;
        const float m0c = (l0 >= 1 && l0 < Ln) ? LOG2E_F * tr[(1 + t0i) * Cn + p0] : 0.0f;
        const float m1c = (l1 < Ln) ? LOG2E_F * tr[(1 + t1i) * Cn + t0i] : 0.0f;
        const float m2c = (l2 < Ln) ? LOG2E_F * tr[(1 + t2i) * Cn + t1i] : 0.0f;

        float a0 = NEGV, a1 = NEGV, a2 = NEGV;
        if (dir == 0) {
            if (k == 0) a0 = LOG2E_F * (tr[t0i] + inp[(size_t)b * Cn + t0i]);
        } else {
            if (k == 49) a2 = 0.0f;   // beta_{T-1}[L-1] = 0
        }

        const int kk = (k < Cn) ? k : (Cn - 1);
        const float* eb = inp + (size_t)b * Cn + kk;  // lane k holds row value k
        const int t0    = dir ? (Tn - 1) : 1;
        const int dt    = dir ? -1 : 1;
        const int steps = dir ? 1000 : 999;

        float ce[8], ne[8];
#pragma unroll
        for (int u = 0; u < 8; ++u) {
            int tt = t0 + u * dt; tt = max(0, min(Tn - 1, tt));
            ce[u] = LOG2E_F * eb[(size_t)tt * (Bn * Cn)];
        }

        for (int s = 0; s < steps; s += 8) {
#pragma unroll
            for (int u = 0; u < 8; ++u) {
                int tt = t0 + (s + 8 + u) * dt; tt = max(0, min(Tn - 1, tt));
                ne[u] = LOG2E_F * eb[(size_t)tt * (Bn * Cn)];
            }
#pragma unroll
            for (int u = 0; u < 8; ++u) {
                if (s + u < steps) {
                    float rv = ce[u];
                    float e0  = __shfl(rv, t0i);   // e_y gathers via bpermute
                    float e1  = __shfl(rv, t1i);
                    float eg2 = __shfl(rv, t2i);
                    if (dir == 0) {
                        float sh = __shfl_up(a2, 1);
                        sh = (k == 0) ? NEGV : sh;
                        float n0 = e0  + ladd2(a0 + s0c, sh + m0c);
                        float n1 = e1  + ladd2(a1 + s1c, a0 + m1c);
                        float n2 = eg2 + ladd2(a2 + s2c, a1 + m2c);
                        a0 = n0; a1 = n1; a2 = n2;
                    } else {
                        float sv0 = a0 + s0c + e0;
                        float mv0 = a0 + m0c + e0;
                        float sv1 = a1 + s1c + e1;
                        float mv1 = a1 + m1c + e1;
                        float sv2 = a2 + s2c + eg2;
                        float mv2 = a2 + m2c + eg2;
                        float mn = __shfl_down(mv0, 1);  // m_{3k+3} from lane k+1
                        mn = (k == 49) ? NEGV : mn;
                        a0 = ladd2(sv0, mv1);
                        a1 = ladd2(sv1, mv2);
                        a2 = ladd2(sv2, mn);
                    }
                }
            }
#pragma unroll
            for (int u = 0; u < 8; ++u) ce[u] = ne[u];
        }
        const int base = (dir ? WS_NUM_B : WS_NUM_F) + b * 160;
        if (l0 < Ln)     ws[base + l0] = a0;
        if (l0 + 1 < Ln) ws[base + l0 + 1] = a1;
        if (l0 + 2 < Ln) ws[base + l0 + 2] = a2;
    }
}

__global__ __launch_bounds__(512)
void asg_combine(const float* __restrict__ ws, float* __restrict__ out)
{
    __shared__ float red[512];
    const int b = threadIdx.x;

    const float* f  = ws + WS_DEN_F + b * 32;
    const float* bk = ws + WS_DEN_B + b * 32;
    float vm = -3.0e38f;
#pragma unroll
    for (int i = 0; i < Cn; ++i) vm = fmaxf(vm, f[i] + bk[i]);
    float sum = 0.f;
#pragma unroll
    for (int i = 0; i < Cn; ++i) sum += FEXP2(f[i] + bk[i] - vm);
    float ld = vm + FLOG2(sum);

    const float* nf = ws + WS_NUM_F + b * 160;
    const float* nb = ws + WS_NUM_B + b * 160;
    float vm2 = -3.0e38f;
    for (int l = 0; l < Ln; ++l) vm2 = fmaxf(vm2, nf[l] + nb[l]);
    float sum2 = 0.f;
    for (int l = 0; l < Ln; ++l) sum2 += FEXP2(nf[l] + nb[l] - vm2);
    float ln = vm2 + FLOG2(sum2);

    red[b] = ld - ln;
    __syncthreads();
    for (int off = 256; off > 0; off >>= 1) {
        if (b < off) red[b] += red[b + off];
        __syncthreads();
    }
    if (b == 0) out[0] = red[0] * (LN2_F / 512.0f);
}

extern "C" void kernel_launch(void* const* d_in, const int* in_sizes, int n_in,
                              void* d_out, int out_size, void* d_ws, size_t ws_size,
                              hipStream_t stream)
{
    const float* inp = (const float*)d_in[0];
    const float* tr  = (const float*)d_in[1];
    const int*   tg  = (const int*)d_in[2];
    float* out = (float*)d_out;
    float* ws  = (float*)d_ws;

    hipLaunchKernelGGL(asg_scan,    dim3(1536), dim3(64),  0, stream, inp, tr, tg, ws);
    hipLaunchKernelGGL(asg_combine, dim3(1),    dim3(512), 0, stream, ws, out);
}